// Round 10
// baseline (348.984 us; speedup 1.0000x reference)
//
#include <hip/hip_runtime.h>
#include <hip/hip_bf16.h>
#include <hip/hip_fp16.h>
#include <cstdint>

#define NFEAT 128
#define NCLS  64
#define TM    64   // nodes per GEMM block tile
#define KT    64   // K-tile (2 tiles of 64 over NFEAT=128)
#define LDP   68   // padded LDS row stride (floats)
#define FIXS  16777216.0f  // 2^24 fixed-point scale for weight sums
#define EPT   4    // edges per thread in accum/fill

typedef unsigned long long u64;
typedef unsigned short u16;

// ---------------- helpers ----------------

__device__ __forceinline__ int load_idx(const void* ei, long long i, int is64) {
  return is64 ? (int)((const long long*)ei)[i] : ((const int*)ei)[i];
}

// init packed histogram; block 0 also detects int64 vs int32 edge_index
// (odd 32-bit words all zero -> int64).
__global__ void k_init(u64* __restrict__ packed, int* __restrict__ flag,
                       const int* __restrict__ ei32, long long total32, int n) {
  int i = blockIdx.x * blockDim.x + threadIdx.x;
  if (i < n) packed[i] = 0ULL;
  if (blockIdx.x == 0) {
    __shared__ int sh[256];
    int tid = threadIdx.x;
    int v = 0;
    for (int j = tid; j < 4096; j += 256) {
      long long idx = 2LL * j + 1;
      if (idx < total32) v |= ei32[idx];
    }
    sh[tid] = v;
    __syncthreads();
    for (int st = 128; st > 0; st >>= 1) {
      if (tid < st) sh[tid] |= sh[tid + st];
      __syncthreads();
    }
    if (tid == 0) flag[0] = (sh[0] == 0) ? 1 : 0;
  }
}

// ONE u64 atomic per edge, EPT edges per thread (independent atomics in
// flight). count in [40:63], sum(w * 2^24) in [0:39]. Returned old count ==
// this edge's rank within its column segment.
__global__ void k_accum(const void* __restrict__ ei, const float* __restrict__ w,
                        const int* __restrict__ flag, u64* __restrict__ packed,
                        u16* __restrict__ rank, int nnz) {
  int is64 = flag[0];
  long long t0 = (long long)blockIdx.x * blockDim.x + threadIdx.x;
  long long stride = (long long)gridDim.x * blockDim.x;
  long long e[EPT];
  int col[EPT];
  float wv[EPT];
  bool val[EPT];
#pragma unroll
  for (int j = 0; j < EPT; ++j) {
    e[j] = t0 + j * stride;
    val[j] = e[j] < nnz;
    col[j] = val[j] ? load_idx(ei, (long long)nnz + e[j], is64) : 0;
    wv[j] = val[j] ? w[e[j]] : 0.f;
  }
  u64 old[EPT];
#pragma unroll
  for (int j = 0; j < EPT; ++j) {
    if (val[j]) {
      u64 add = (1ULL << 40) | (u64)(unsigned int)__float2uint_rn(wv[j] * FIXS);
      old[j] = atomicAdd(&packed[col[j]], add);
    }
  }
#pragma unroll
  for (int j = 0; j < EPT; ++j)
    if (val[j]) rank[e[j]] = (u16)(old[j] >> 40);
}

// scan part A: per-1024 block exclusive scan of counts (from packed) + sums
__global__ void k_scanA(const u64* __restrict__ packed, int* __restrict__ off,
                        int* __restrict__ bsums, int n) {
  __shared__ int sh[256];
  int tid = threadIdx.x;
  int base = blockIdx.x * 1024 + tid * 4;
  int v[4];
#pragma unroll
  for (int j = 0; j < 4; ++j)
    v[j] = (base + j < n) ? (int)(packed[base + j] >> 40) : 0;
  int tsum = v[0] + v[1] + v[2] + v[3];
  int val = tsum;
  sh[tid] = val;
  __syncthreads();
  for (int ofs = 1; ofs < 256; ofs <<= 1) {
    int t = (tid >= ofs) ? sh[tid - ofs] : 0;
    __syncthreads();
    val += t;
    sh[tid] = val;
    __syncthreads();
  }
  int run = val - tsum;
#pragma unroll
  for (int j = 0; j < 4; ++j) {
    if (base + j < n) off[base + j] = run;
    run += v[j];
  }
  if (tid == 255) bsums[blockIdx.x] = val;
}

// scan part B + epilogue: finalize exclusive offsets -> offx[n+1];
// dis = rsqrt(1 + fixsum/2^24).
__global__ void k_scanB(const int* __restrict__ off, const int* __restrict__ bsums,
                        const u64* __restrict__ packed, int* __restrict__ offx,
                        float* __restrict__ dis, int n, int nnz) {
  __shared__ int sh[256];
  int tid = threadIdx.x;
  int s = 0;
  for (int j = tid; j < (int)blockIdx.x; j += 256) s += bsums[j];
  sh[tid] = s;
  __syncthreads();
  for (int st = 128; st > 0; st >>= 1) {
    if (tid < st) sh[tid] += sh[tid + st];
    __syncthreads();
  }
  int prefix = sh[0];
  int base = blockIdx.x * 1024 + tid * 4;
#pragma unroll
  for (int j = 0; j < 4; ++j) {
    int i = base + j;
    if (i < n) {
      u64 p = packed[i];
      offx[i] = off[i] + prefix;
      dis[i] = rsqrtf(1.0f + (float)(p & ((1ULL << 40) - 1)) * (1.0f / FIXS));
    }
  }
  if (blockIdx.x == 0 && tid == 0) offx[n] = nnz;
}

// atomic-free CSC fill with RAW weights: pos = offx[col] + rank[e].
// EPT edges per thread for gather/scatter MLP.
__global__ void k_fill(const void* __restrict__ ei, const float* __restrict__ w,
                       const int* __restrict__ flag, const int* __restrict__ offx,
                       const u16* __restrict__ rank, int2* __restrict__ csc,
                       int nnz) {
  int is64 = flag[0];
  long long t0 = (long long)blockIdx.x * blockDim.x + threadIdx.x;
  long long stride = (long long)gridDim.x * blockDim.x;
#pragma unroll
  for (int j = 0; j < EPT; ++j) {
    long long e = t0 + j * stride;
    if (e < nnz) {
      int row = load_idx(ei, e, is64);
      int col = load_idx(ei, (long long)nnz + e, is64);
      csc[offx[col] + (int)rank[e]] = make_int2(row, __float_as_int(w[e]));
    }
  }
}

// v = dis * (X @ W^T), LDS-tiled (two 64-wide K-tiles), fp16 output.
__global__ __launch_bounds__(256) void k_gemm(const float* __restrict__ x,
                                              const float* __restrict__ w,
                                              const float* __restrict__ dis,
                                              __half* __restrict__ y, int n) {
  __shared__ float xt[KT][LDP];
  __shared__ float wt[KT][LDP];
  int t = threadIdx.x;
  int bm = blockIdx.x * TM;

  int tn = t & 15;
  int tc = t >> 4;
  float acc[4][4];
#pragma unroll
  for (int a = 0; a < 4; ++a)
#pragma unroll
    for (int b = 0; b < 4; ++b) acc[a][b] = 0.f;

  for (int kt = 0; kt < NFEAT; kt += KT) {
    __syncthreads();
    for (int i = t; i < NCLS * KT; i += 256) {
      int kk = i & (KT - 1), cls = i >> 6;
      wt[kk][cls] = w[(size_t)cls * NFEAT + kt + kk];
    }
    int k0   = (t & 15) * 4;
    int nloc = t >> 4;
#pragma unroll
    for (int i = 0; i < 4; ++i) {
      int node = bm + nloc + 16 * i;
      float4 v = make_float4(0.f, 0.f, 0.f, 0.f);
      if (node < n) v = *(const float4*)(x + (size_t)node * NFEAT + kt + k0);
      xt[k0 + 0][nloc + 16 * i] = v.x;
      xt[k0 + 1][nloc + 16 * i] = v.y;
      xt[k0 + 2][nloc + 16 * i] = v.z;
      xt[k0 + 3][nloc + 16 * i] = v.w;
    }
    __syncthreads();

#pragma unroll 4
    for (int k = 0; k < KT; ++k) {
      float4 xv = *(const float4*)&xt[k][tn * 4];
      float4 wv = *(const float4*)&wt[k][tc * 4];
      acc[0][0] += xv.x * wv.x; acc[0][1] += xv.x * wv.y;
      acc[0][2] += xv.x * wv.z; acc[0][3] += xv.x * wv.w;
      acc[1][0] += xv.y * wv.x; acc[1][1] += xv.y * wv.y;
      acc[1][2] += xv.y * wv.z; acc[1][3] += xv.y * wv.w;
      acc[2][0] += xv.z * wv.x; acc[2][1] += xv.z * wv.y;
      acc[2][2] += xv.z * wv.z; acc[2][3] += xv.z * wv.w;
      acc[3][0] += xv.w * wv.x; acc[3][1] += xv.w * wv.y;
      acc[3][2] += xv.w * wv.z; acc[3][3] += xv.w * wv.w;
    }
  }

#pragma unroll
  for (int a = 0; a < 4; ++a) {
    int node = bm + tn * 4 + a;
    if (node < n) {
      float d = dis[node];
      __half2* dst = (__half2*)(y + (size_t)node * NCLS + tc * 4);
      dst[0] = __floats2half2_rn(d * acc[a][0], d * acc[a][1]);
      dst[1] = __floats2half2_rn(d * acc[a][2], d * acc[a][3]);
    }
  }
}

// one hop with RAW weights over fp16: acc = yin[c] + sum w_e * yin[row_e].
// FINAL=0: write fp16 dis^2 * acc.  FINAL=1: write f32 dis * acc + bias.
template <int FINAL>
__global__ void k_hop(const __half* __restrict__ yin, __half* __restrict__ youth,
                      float* __restrict__ youtf, const int* __restrict__ offx,
                      const int2* __restrict__ csc, const float* __restrict__ dis,
                      const float* __restrict__ bias, int n) {
  int node = (blockIdx.x * blockDim.x + threadIdx.x) >> 6;
  int lane = threadIdx.x & 63;
  if (node >= n) return;
  int beg = offx[node];
  int end = offx[node + 1];
  float acc = __half2float(yin[(size_t)node * NCLS + lane]);  // self loop, w=1

  for (int base = beg; base < end; base += 64) {
    int cnt = min(64, end - base);
    int2 m = make_int2(0, 0);
    if (lane < cnt) m = csc[base + lane];
    int e = 0;
    for (; e + 8 <= cnt; e += 8) {
      int r[8];
      float wv[8], v[8];
#pragma unroll
      for (int j = 0; j < 8; ++j) {
        r[j] = __builtin_amdgcn_readlane(m.x, e + j);
        wv[j] = __int_as_float(__builtin_amdgcn_readlane(m.y, e + j));
      }
#pragma unroll
      for (int j = 0; j < 8; ++j)
        v[j] = __half2float(yin[(size_t)r[j] * NCLS + lane]);
#pragma unroll
      for (int j = 0; j < 8; ++j) acc += wv[j] * v[j];
    }
    for (; e < cnt; ++e) {
      int r = __builtin_amdgcn_readlane(m.x, e);
      float wv = __int_as_float(__builtin_amdgcn_readlane(m.y, e));
      acc += wv * __half2float(yin[(size_t)r * NCLS + lane]);
    }
  }
  float d = dis[node];
  if (FINAL) {
    youtf[(size_t)node * NCLS + lane] = d * acc + bias[lane];
  } else {
    youth[(size_t)node * NCLS + lane] = __float2half(d * d * acc);
  }
}

// ---------------- launch ----------------

extern "C" void kernel_launch(void* const* d_in, const int* in_sizes, int n_in,
                              void* d_out, int out_size, void* d_ws, size_t ws_size,
                              hipStream_t stream) {
  (void)n_in; (void)out_size; (void)ws_size;
  const float* x  = (const float*)d_in[0];
  const void*  ei = d_in[1];
  const float* ew = (const float*)d_in[2];
  const float* lw = (const float*)d_in[3];
  const float* lb = (const float*)d_in[4];
  float* out = (float*)d_out;

  int n   = in_sizes[0] / NFEAT;
  int nnz = in_sizes[1] / 2;

  char* p = (char*)d_ws;
  auto carve = [&](size_t bytes) -> char* {
    char* r = p;
    p += (bytes + 255) & ~(size_t)255;
    return r;
  };
  int*    flag   = (int*)carve(4);
  u64*    packed = (u64*)carve((size_t)n * 8);
  u16*    rank   = (u16*)carve((size_t)nnz * 2);
  int*    off    = (int*)carve((size_t)n * 4);
  int     nsb    = (n + 1023) / 1024;
  int*    bsums  = (int*)carve((size_t)nsb * 4);
  int*    offx   = (int*)carve((size_t)(n + 1) * 4);
  float*  dis    = (float*)carve((size_t)n * 4);
  int2*   csc    = (int2*)carve((size_t)nnz * 8);
  __half* y0     = (__half*)carve((size_t)n * NCLS * 2);
  __half* y1     = (__half*)carve((size_t)n * NCLS * 2);

  int gb = (n + 255) / 256;
  int ge = (nnz / EPT + 255) / 256;   // EPT edges per thread
  int gw = (n + 3) / 4;               // hop: 4 node-waves per 256-thread block
  int gg = (n + TM - 1) / TM;         // gemm tiles

  k_init<<<gb, 256, 0, stream>>>(packed, flag, (const int*)ei, 2LL * nnz, n);
  k_accum<<<ge, 256, 0, stream>>>(ei, ew, flag, packed, rank, nnz);
  k_scanA<<<nsb, 256, 0, stream>>>(packed, off, bsums, n);
  k_scanB<<<nsb, 256, 0, stream>>>(off, bsums, packed, offx, dis, n, nnz);
  k_fill<<<ge, 256, 0, stream>>>(ei, ew, flag, offx, rank, csc, nnz);
  k_gemm<<<gg, 256, 0, stream>>>(x, lw, dis, y0, n);
  k_hop<0><<<gw, 256, 0, stream>>>(y0, y1, nullptr, offx, csc, dis, nullptr, n);
  k_hop<1><<<gw, 256, 0, stream>>>(y1, nullptr, out, offx, csc, dis, lb, n);
}

// Round 11
// 314.672 us; speedup vs baseline: 1.1090x; 1.1090x over previous
//
#include <hip/hip_runtime.h>
#include <hip/hip_bf16.h>
#include <hip/hip_fp16.h>
#include <cstdint>

#define NFEAT 128
#define NCLS  64
#define TM    64    // nodes per GEMM block tile
#define KT    64    // K-tile
#define LDP   68    // padded LDS row stride (floats)
#define BSH   7     // bucket shift: 128 cols per bucket
#define BCOLS 128
#define NBLK  256   // blocks in bucket-count/scatter passes
#define WFIX  1048576.0f  // 2^20 fixed-point scale for per-col weight sums

typedef unsigned long long u64;

// ---------------- helpers ----------------

__device__ __forceinline__ int load_idx(const void* ei, long long i, int is64) {
  return is64 ? (int)((const long long*)ei)[i] : ((const int*)ei)[i];
}

// Detect int64 vs int32 edge_index (odd 32-bit words all zero -> int64).
__global__ void k_detect(const int* __restrict__ ei32, int* __restrict__ flag,
                         long long total32) {
  __shared__ int sh[256];
  int tid = threadIdx.x;
  int v = 0;
  for (int i = tid; i < 4096; i += 256) {
    long long idx = 2LL * i + 1;
    if (idx < total32) v |= ei32[idx];
  }
  sh[tid] = v;
  __syncthreads();
  for (int st = 128; st > 0; st >>= 1) {
    if (tid < st) sh[tid] |= sh[tid + st];
    __syncthreads();
  }
  if (tid == 0) flag[0] = (sh[0] == 0) ? 1 : 0;
}

// Pass A: per-block LDS histogram of bucket ids -> bcnt[block][bucket]
__global__ void k_bcount(const void* __restrict__ ei, const int* __restrict__ flag,
                         int* __restrict__ bcnt, int nnz, int nb, int eb) {
  extern __shared__ int lh[];
  int t = threadIdx.x;
  for (int j = t; j < nb; j += 256) lh[j] = 0;
  __syncthreads();
  int is64 = flag[0];
  long long beg = (long long)blockIdx.x * eb;
  long long end = beg + eb; if (end > nnz) end = nnz;
  for (long long i = beg + t; i < end; i += 256) {
    int col = load_idx(ei, (long long)nnz + i, is64);
    atomicAdd(&lh[col >> BSH], 1);
  }
  __syncthreads();
  for (int j = t; j < nb; j += 256) bcnt[(size_t)blockIdx.x * nb + j] = lh[j];
}

// Pass A2: for bucket j (= blockIdx.x), exclusive scan bcnt[0..NBLK)[j] in
// place; total -> tot[j].
__global__ void k_colscan(int* __restrict__ bcnt, int* __restrict__ tot, int nb) {
  __shared__ int sh[NBLK];
  int j = blockIdx.x;
  int t = threadIdx.x;
  int v = bcnt[(size_t)t * nb + j];
  int val = v;
  sh[t] = val;
  __syncthreads();
  for (int ofs = 1; ofs < NBLK; ofs <<= 1) {
    int x = (t >= ofs) ? sh[t - ofs] : 0;
    __syncthreads();
    val += x;
    sh[t] = val;
    __syncthreads();
  }
  bcnt[(size_t)t * nb + j] = val - v;
  if (t == NBLK - 1) tot[j] = val;
}

// Pass A3: exclusive scan of bucket totals -> bbase[nb+1]; offx[n] = nnz.
__global__ void k_bucketscan(const int* __restrict__ tot, int* __restrict__ bbase,
                             int* __restrict__ offx, int nb, int n, int nnz) {
  __shared__ int sh[256];
  int t = threadIdx.x;
  int base = t * 4;
  int v[4];
#pragma unroll
  for (int j = 0; j < 4; ++j) v[j] = (base + j < nb) ? tot[base + j] : 0;
  int tsum = v[0] + v[1] + v[2] + v[3];
  int val = tsum;
  sh[t] = val;
  __syncthreads();
  for (int ofs = 1; ofs < 256; ofs <<= 1) {
    int x = (t >= ofs) ? sh[t - ofs] : 0;
    __syncthreads();
    val += x;
    sh[t] = val;
    __syncthreads();
  }
  int run = val - tsum;
#pragma unroll
  for (int j = 0; j < 4; ++j) {
    if (base + j < nb) bbase[base + j] = run;
    run += v[j];
  }
  if (t == 0) { bbase[nb] = nnz; offx[n] = nnz; }
}

// Pass B: scatter edge records into bucket-grouped ebuf via LDS cursors.
__global__ void k_bscatter(const void* __restrict__ ei, const float* __restrict__ w,
                           const int* __restrict__ flag, const int* __restrict__ bcnt,
                           const int* __restrict__ bbase, int4* __restrict__ ebuf,
                           int nnz, int nb, int eb) {
  extern __shared__ int cur[];
  int t = threadIdx.x;
  for (int j = t; j < nb; j += 256)
    cur[j] = bbase[j] + bcnt[(size_t)blockIdx.x * nb + j];
  __syncthreads();
  int is64 = flag[0];
  long long beg = (long long)blockIdx.x * eb;
  long long end = beg + eb; if (end > nnz) end = nnz;
  for (long long i = beg + t; i < end; i += 256) {
    int col = load_idx(ei, (long long)nnz + i, is64);
    int row = load_idx(ei, i, is64);
    float wv = w[i];
    int pos = atomicAdd(&cur[col >> BSH], 1);
    ebuf[pos] = make_int4(col, row, __float_as_int(wv), 0);
  }
}

// Pass C: per bucket (block, 128 threads): LDS count + weight-sum over its
// <=128 cols, LDS scan -> offx, dis, and CSC records. No global atomics.
__global__ __launch_bounds__(BCOLS) void k_bbuild(
    const int4* __restrict__ ebuf, const int* __restrict__ bbase,
    int* __restrict__ offx, float* __restrict__ dis, int2* __restrict__ csc,
    int n, int nb) {
  __shared__ int lh[BCOLS], lw[BCOLS], lofs[BCOLS], sh[BCOLS];
  int j = blockIdx.x;
  int t = threadIdx.x;
  int col0 = j << BSH;
  int bb0 = bbase[j], bb1 = bbase[j + 1];
  lh[t] = 0; lw[t] = 0;
  __syncthreads();
  for (int i = bb0 + t; i < bb1; i += BCOLS) {
    int4 r = ebuf[i];
    int c = r.x - col0;
    atomicAdd(&lh[c], 1);
    atomicAdd(&lw[c], (int)rintf(__int_as_float(r.z) * WFIX));
  }
  __syncthreads();
  int v = lh[t];
  int val = v;
  sh[t] = val;
  __syncthreads();
  for (int ofs = 1; ofs < BCOLS; ofs <<= 1) {
    int x = (t >= ofs) ? sh[t - ofs] : 0;
    __syncthreads();
    val += x;
    sh[t] = val;
    __syncthreads();
  }
  lofs[t] = val - v;
  int col = col0 + t;
  if (col < n) {
    offx[col] = bb0 + lofs[t];
    dis[col] = rsqrtf(1.0f + (float)lw[t] * (1.0f / WFIX));
  }
  lh[t] = 0;  // reuse as per-col cursor
  __syncthreads();
  for (int i = bb0 + t; i < bb1; i += BCOLS) {
    int4 r = ebuf[i];
    int c = r.x - col0;
    int p = bb0 + lofs[c] + atomicAdd(&lh[c], 1);
    csc[p] = make_int2(r.y, r.z);
  }
}

// v = dis * (X @ W^T), LDS-tiled (two 64-wide K-tiles), fp16 output.
__global__ __launch_bounds__(256) void k_gemm(const float* __restrict__ x,
                                              const float* __restrict__ w,
                                              const float* __restrict__ dis,
                                              __half* __restrict__ y, int n) {
  __shared__ float xt[KT][LDP];
  __shared__ float wt[KT][LDP];
  int t = threadIdx.x;
  int bm = blockIdx.x * TM;

  int tn = t & 15;
  int tc = t >> 4;
  float acc[4][4];
#pragma unroll
  for (int a = 0; a < 4; ++a)
#pragma unroll
    for (int b = 0; b < 4; ++b) acc[a][b] = 0.f;

  for (int kt = 0; kt < NFEAT; kt += KT) {
    __syncthreads();
    for (int i = t; i < NCLS * KT; i += 256) {
      int kk = i & (KT - 1), cls = i >> 6;
      wt[kk][cls] = w[(size_t)cls * NFEAT + kt + kk];
    }
    int k0   = (t & 15) * 4;
    int nloc = t >> 4;
#pragma unroll
    for (int i = 0; i < 4; ++i) {
      int node = bm + nloc + 16 * i;
      float4 v = make_float4(0.f, 0.f, 0.f, 0.f);
      if (node < n) v = *(const float4*)(x + (size_t)node * NFEAT + kt + k0);
      xt[k0 + 0][nloc + 16 * i] = v.x;
      xt[k0 + 1][nloc + 16 * i] = v.y;
      xt[k0 + 2][nloc + 16 * i] = v.z;
      xt[k0 + 3][nloc + 16 * i] = v.w;
    }
    __syncthreads();

#pragma unroll 4
    for (int k = 0; k < KT; ++k) {
      float4 xv = *(const float4*)&xt[k][tn * 4];
      float4 wv = *(const float4*)&wt[k][tc * 4];
      acc[0][0] += xv.x * wv.x; acc[0][1] += xv.x * wv.y;
      acc[0][2] += xv.x * wv.z; acc[0][3] += xv.x * wv.w;
      acc[1][0] += xv.y * wv.x; acc[1][1] += xv.y * wv.y;
      acc[1][2] += xv.y * wv.z; acc[1][3] += xv.y * wv.w;
      acc[2][0] += xv.z * wv.x; acc[2][1] += xv.z * wv.y;
      acc[2][2] += xv.z * wv.z; acc[2][3] += xv.z * wv.w;
      acc[3][0] += xv.w * wv.x; acc[3][1] += xv.w * wv.y;
      acc[3][2] += xv.w * wv.z; acc[3][3] += xv.w * wv.w;
    }
  }

#pragma unroll
  for (int a = 0; a < 4; ++a) {
    int node = bm + tn * 4 + a;
    if (node < n) {
      float d = dis[node];
      __half2* dst = (__half2*)(y + (size_t)node * NCLS + tc * 4);
      dst[0] = __floats2half2_rn(d * acc[a][0], d * acc[a][1]);
      dst[1] = __floats2half2_rn(d * acc[a][2], d * acc[a][3]);
    }
  }
}

// one hop with RAW weights over fp16: acc = yin[c] + sum w_e * yin[row_e].
// FINAL=0: write fp16 dis^2 * acc.  FINAL=1: write f32 dis * acc + bias.
template <int FINAL>
__global__ void k_hop(const __half* __restrict__ yin, __half* __restrict__ youth,
                      float* __restrict__ youtf, const int* __restrict__ offx,
                      const int2* __restrict__ csc, const float* __restrict__ dis,
                      const float* __restrict__ bias, int n) {
  int node = (blockIdx.x * blockDim.x + threadIdx.x) >> 6;
  int lane = threadIdx.x & 63;
  if (node >= n) return;
  int beg = offx[node];
  int end = offx[node + 1];
  float acc = __half2float(yin[(size_t)node * NCLS + lane]);  // self loop, w=1

  for (int base = beg; base < end; base += 64) {
    int cnt = min(64, end - base);
    int2 m = make_int2(0, 0);
    if (lane < cnt) m = csc[base + lane];
    int e = 0;
    for (; e + 8 <= cnt; e += 8) {
      int r[8];
      float wv[8], v[8];
#pragma unroll
      for (int j = 0; j < 8; ++j) {
        r[j] = __builtin_amdgcn_readlane(m.x, e + j);
        wv[j] = __int_as_float(__builtin_amdgcn_readlane(m.y, e + j));
      }
#pragma unroll
      for (int j = 0; j < 8; ++j)
        v[j] = __half2float(yin[(size_t)r[j] * NCLS + lane]);
#pragma unroll
      for (int j = 0; j < 8; ++j) acc += wv[j] * v[j];
    }
    for (; e < cnt; ++e) {
      int r = __builtin_amdgcn_readlane(m.x, e);
      float wv = __int_as_float(__builtin_amdgcn_readlane(m.y, e));
      acc += wv * __half2float(yin[(size_t)r * NCLS + lane]);
    }
  }
  float d = dis[node];
  if (FINAL) {
    youtf[(size_t)node * NCLS + lane] = d * acc + bias[lane];
  } else {
    youth[(size_t)node * NCLS + lane] = __float2half(d * d * acc);
  }
}

// ---------------- launch ----------------

extern "C" void kernel_launch(void* const* d_in, const int* in_sizes, int n_in,
                              void* d_out, int out_size, void* d_ws, size_t ws_size,
                              hipStream_t stream) {
  (void)n_in; (void)out_size; (void)ws_size;
  const float* x  = (const float*)d_in[0];
  const void*  ei = d_in[1];
  const float* ew = (const float*)d_in[2];
  const float* lw = (const float*)d_in[3];
  const float* lb = (const float*)d_in[4];
  float* out = (float*)d_out;

  int n   = in_sizes[0] / NFEAT;
  int nnz = in_sizes[1] / 2;
  int nb  = (n + BCOLS - 1) >> BSH;       // buckets of 128 cols
  int eb  = (nnz + NBLK - 1) / NBLK;      // edges per block in A/B

  char* p = (char*)d_ws;
  auto carve = [&](size_t bytes) -> char* {
    char* r = p;
    p += (bytes + 255) & ~(size_t)255;
    return r;
  };
  int*    flag  = (int*)carve(4);
  int*    bcnt  = (int*)carve((size_t)NBLK * nb * 4);
  int*    tot   = (int*)carve((size_t)nb * 4);
  int*    bbase = (int*)carve((size_t)(nb + 1) * 4);
  int*    offx  = (int*)carve((size_t)(n + 1) * 4);
  float*  dis   = (float*)carve((size_t)n * 4);
  int2*   csc   = (int2*)carve((size_t)nnz * 8);
  __half* y0    = (__half*)carve((size_t)n * NCLS * 2);
  __half* y1    = (__half*)carve((size_t)n * NCLS * 2);
  // ebuf (nnz * 16B) aliases d_out (n*NCLS*4B >= nnz*16 here); dead before
  // the final hop writes d_out.
  int4*   ebuf  = (int4*)d_out;

  int gw = (n + 3) / 4;               // hop: 4 node-waves per 256-thread block
  int gg = (n + TM - 1) / TM;         // gemm tiles

  k_detect<<<1, 256, 0, stream>>>((const int*)ei, flag, 2LL * nnz);
  k_bcount<<<NBLK, 256, nb * 4, stream>>>(ei, flag, bcnt, nnz, nb, eb);
  k_colscan<<<nb, NBLK, 0, stream>>>(bcnt, tot, nb);
  k_bucketscan<<<1, 256, 0, stream>>>(tot, bbase, offx, nb, n, nnz);
  k_bscatter<<<NBLK, 256, nb * 4, stream>>>(ei, ew, flag, bcnt, bbase, ebuf,
                                            nnz, nb, eb);
  k_bbuild<<<nb, BCOLS, 0, stream>>>(ebuf, bbase, offx, dis, csc, n, nb);
  k_gemm<<<gg, 256, 0, stream>>>(x, lw, dis, y0, n);
  k_hop<0><<<gw, 256, 0, stream>>>(y0, y1, nullptr, offx, csc, dis, nullptr, n);
  k_hop<1><<<gw, 256, 0, stream>>>(y1, nullptr, out, offx, csc, dis, lb, n);
}

// Round 12
// 286.972 us; speedup vs baseline: 1.2161x; 1.0965x over previous
//
#include <hip/hip_runtime.h>
#include <hip/hip_fp16.h>
#include <cstdint>

#define NFEAT 128
#define NCLS  64
#define TM    64    // nodes per GEMM block tile
#define KT    64    // K-tile
#define LDP   68    // padded LDS row stride (floats)
#define BSH   7     // bucket shift: 128 cols per bucket
#define BCOLS 128
#define NBLK  256   // blocks in count/scatter passes
#define WFIX  1048576.0f  // 2^20 fixed-point scale for per-col weight sums
#define STAGECAP 4096     // LDS csc staging capacity (records)

typedef unsigned long long u64;
typedef unsigned int u32;

// ---------------- helpers ----------------

__device__ __forceinline__ int load_idx(const void* ei, long long i, int is64) {
  return is64 ? (int)((const long long*)ei)[i] : ((const int*)ei)[i];
}

// Per-block redundant int64-vs-int32 detection (odd 32-bit words of an
// int64 non-negative index array are all zero). Reads a fixed 4096-word
// sample (L2-hot after the first block). sh = 256-int scratch.
__device__ int detect_is64(const int* ei32, long long total32, int* sh) {
  int tid = threadIdx.x;
  int v = 0;
  for (int i = tid; i < 4096; i += 256) {
    long long idx = 2LL * i + 1;
    if (idx < total32) v |= ei32[idx];
  }
  sh[tid] = v;
  __syncthreads();
  for (int st = 128; st > 0; st >>= 1) {
    if (tid < st) sh[tid] |= sh[tid + st];
    __syncthreads();
  }
  int r = (sh[0] == 0) ? 1 : 0;
  __syncthreads();  // sh is reused by callers
  return r;
}

// Exclusive scan of tot[0..nb) using 256 threads (nb <= 1024); results into
// dst[i] (+ optional per-block addend from bcnt row). sh = 256-int scratch.
__device__ void scan_tot(const int* __restrict__ tot, int* dst, int nb,
                         int* sh, const int* __restrict__ bcnt_row) {
  int t = threadIdx.x;
  int base = t * 4;
  int v[4];
#pragma unroll
  for (int j = 0; j < 4; ++j) v[j] = (base + j < nb) ? tot[base + j] : 0;
  int tsum = v[0] + v[1] + v[2] + v[3];
  int val = tsum;
  sh[t] = val;
  __syncthreads();
  for (int ofs = 1; ofs < 256; ofs <<= 1) {
    int x = (t >= ofs) ? sh[t - ofs] : 0;
    __syncthreads();
    val += x;
    sh[t] = val;
    __syncthreads();
  }
  int run = val - tsum;
#pragma unroll
  for (int j = 0; j < 4; ++j) {
    if (base + j < nb)
      dst[base + j] = run + (bcnt_row ? bcnt_row[base + j] : 0);
    run += v[j];
  }
  __syncthreads();
}

// Pass A: per-block LDS histogram of bucket ids -> bcnt[block][bucket]
__global__ __launch_bounds__(256) void k_bcount(const void* __restrict__ ei,
                                                int* __restrict__ bcnt,
                                                int nnz, int nb, int eb) {
  __shared__ int sh[256];
  extern __shared__ int lh[];
  int t = threadIdx.x;
  int is64 = detect_is64((const int*)ei, 2LL * nnz, sh);
  for (int j = t; j < nb; j += 256) lh[j] = 0;
  __syncthreads();
  long long beg = (long long)blockIdx.x * eb;
  long long end = beg + eb; if (end > nnz) end = nnz;
  for (long long i = beg + t; i < end; i += 256) {
    int col = load_idx(ei, (long long)nnz + i, is64);
    atomicAdd(&lh[col >> BSH], 1);
  }
  __syncthreads();
  for (int j = t; j < nb; j += 256) bcnt[(size_t)blockIdx.x * nb + j] = lh[j];
}

// Pass A2: for bucket j, exclusive scan bcnt[0..NBLK)[j] in place; total->tot.
__global__ void k_colscan(int* __restrict__ bcnt, int* __restrict__ tot, int nb) {
  __shared__ int sh[NBLK];
  int j = blockIdx.x;
  int t = threadIdx.x;
  int v = bcnt[(size_t)t * nb + j];
  int val = v;
  sh[t] = val;
  __syncthreads();
  for (int ofs = 1; ofs < NBLK; ofs <<= 1) {
    int x = (t >= ofs) ? sh[t - ofs] : 0;
    __syncthreads();
    val += x;
    sh[t] = val;
    __syncthreads();
  }
  bcnt[(size_t)t * nb + j] = val - v;
  if (t == NBLK - 1) tot[j] = val;
}

// Pass B: scatter 8-B packed edge records into bucket-grouped ebuf.
// Record: [63:49] colLow(7b)<<17|... meta = row | colLow<<17 in high word,
// w f32 bits in low word.
__global__ __launch_bounds__(256) void k_bscatter(
    const void* __restrict__ ei, const float* __restrict__ w,
    const int* __restrict__ bcnt, const int* __restrict__ tot,
    u64* __restrict__ ebuf, int nnz, int nb, int eb) {
  __shared__ int sh[256];
  extern __shared__ int cur[];  // nb cursors
  int t = threadIdx.x;
  int is64 = detect_is64((const int*)ei, 2LL * nnz, sh);
  scan_tot(tot, cur, nb, sh, bcnt + (size_t)blockIdx.x * nb);
  long long beg = (long long)blockIdx.x * eb;
  long long end = beg + eb; if (end > nnz) end = nnz;
  for (long long i = beg + t; i < end; i += 256) {
    int col = load_idx(ei, (long long)nnz + i, is64);
    int row = load_idx(ei, i, is64);
    float wv = w[i];
    int pos = atomicAdd(&cur[col >> BSH], 1);
    u64 meta = (u64)(u32)(row | ((col & (BCOLS - 1)) << 17));
    ebuf[pos] = (meta << 32) | (u64)(u32)__float_as_int(wv);
  }
}

// Pass C: per bucket: LDS count + weight-sum over its <=128 cols, LDS scan
// -> offx, dis; csc built in LDS staging then streamed out coalesced.
__global__ __launch_bounds__(256) void k_bbuild(
    const u64* __restrict__ ebuf, const int* __restrict__ tot,
    int* __restrict__ offx, float* __restrict__ dis, int2* __restrict__ csc,
    int n, int nb, int nnz) {
  __shared__ int sh[256];
  __shared__ int sgb[1025];
  __shared__ int lh[BCOLS], lws[BCOLS], lofs[BCOLS];
  __shared__ u64 stage[STAGECAP];
  int j = blockIdx.x;
  int t = threadIdx.x;
  scan_tot(tot, sgb, nb, sh, nullptr);
  if (t == 0) sgb[nb] = nnz;
  __syncthreads();
  int bb0 = sgb[j], bb1 = sgb[j + 1];
  int cnt = bb1 - bb0;
  if (t < BCOLS) { lh[t] = 0; lws[t] = 0; }
  __syncthreads();
  for (int i = bb0 + t; i < bb1; i += 256) {
    u64 p = ebuf[i];
    int c = (int)((p >> 49) & 0x7F);
    atomicAdd(&lh[c], 1);
    atomicAdd(&lws[c], (int)rintf(__int_as_float((int)(u32)p) * WFIX));
  }
  __syncthreads();
  int vv = (t < BCOLS) ? lh[t] : 0;
  int val = vv;
  sh[t] = val;
  __syncthreads();
  for (int ofs = 1; ofs < 256; ofs <<= 1) {
    int x = (t >= ofs) ? sh[t - ofs] : 0;
    __syncthreads();
    val += x;
    sh[t] = val;
    __syncthreads();
  }
  if (t < BCOLS) {
    lofs[t] = val - vv;
    int col = (j << BSH) + t;
    if (col < n) {
      offx[col] = bb0 + lofs[t];
      dis[col] = rsqrtf(1.0f + (float)lws[t] * (1.0f / WFIX));
    }
    lh[t] = 0;  // reuse as per-col cursor
  }
  if (j == 0 && t == 0) offx[n] = nnz;
  __syncthreads();
  bool direct = cnt > STAGECAP;
  for (int i = bb0 + t; i < bb1; i += 256) {
    u64 p = ebuf[i];
    int c = (int)((p >> 49) & 0x7F);
    int row = (int)((p >> 32) & 0x1FFFF);
    int pos = lofs[c] + atomicAdd(&lh[c], 1);
    if (direct) csc[bb0 + pos] = make_int2(row, (int)(u32)p);
    else stage[pos] = ((u64)(u32)p << 32) | (u64)(u32)row;
  }
  __syncthreads();
  if (!direct) {
    for (int i = t; i < cnt; i += 256) {
      u64 s = stage[i];
      csc[bb0 + i] = make_int2((int)(u32)s, (int)(s >> 32));
    }
  }
}

// v = dis * (X @ W^T), LDS-tiled (two 64-wide K-tiles), fp16 output.
__global__ __launch_bounds__(256) void k_gemm(const float* __restrict__ x,
                                              const float* __restrict__ w,
                                              const float* __restrict__ dis,
                                              __half* __restrict__ y, int n) {
  __shared__ float xt[KT][LDP];
  __shared__ float wt[KT][LDP];
  int t = threadIdx.x;
  int bm = blockIdx.x * TM;

  int tn = t & 15;
  int tc = t >> 4;
  float acc[4][4];
#pragma unroll
  for (int a = 0; a < 4; ++a)
#pragma unroll
    for (int b = 0; b < 4; ++b) acc[a][b] = 0.f;

  for (int kt = 0; kt < NFEAT; kt += KT) {
    __syncthreads();
    for (int i = t; i < NCLS * KT; i += 256) {
      int kk = i & (KT - 1), cls = i >> 6;
      wt[kk][cls] = w[(size_t)cls * NFEAT + kt + kk];
    }
    int k0   = (t & 15) * 4;
    int nloc = t >> 4;
#pragma unroll
    for (int i = 0; i < 4; ++i) {
      int node = bm + nloc + 16 * i;
      float4 v = make_float4(0.f, 0.f, 0.f, 0.f);
      if (node < n) v = *(const float4*)(x + (size_t)node * NFEAT + kt + k0);
      xt[k0 + 0][nloc + 16 * i] = v.x;
      xt[k0 + 1][nloc + 16 * i] = v.y;
      xt[k0 + 2][nloc + 16 * i] = v.z;
      xt[k0 + 3][nloc + 16 * i] = v.w;
    }
    __syncthreads();

#pragma unroll 4
    for (int k = 0; k < KT; ++k) {
      float4 xv = *(const float4*)&xt[k][tn * 4];
      float4 wv = *(const float4*)&wt[k][tc * 4];
      acc[0][0] += xv.x * wv.x; acc[0][1] += xv.x * wv.y;
      acc[0][2] += xv.x * wv.z; acc[0][3] += xv.x * wv.w;
      acc[1][0] += xv.y * wv.x; acc[1][1] += xv.y * wv.y;
      acc[1][2] += xv.y * wv.z; acc[1][3] += xv.y * wv.w;
      acc[2][0] += xv.z * wv.x; acc[2][1] += xv.z * wv.y;
      acc[2][2] += xv.z * wv.z; acc[2][3] += xv.z * wv.w;
      acc[3][0] += xv.w * wv.x; acc[3][1] += xv.w * wv.y;
      acc[3][2] += xv.w * wv.z; acc[3][3] += xv.w * wv.w;
    }
  }

#pragma unroll
  for (int a = 0; a < 4; ++a) {
    int node = bm + tn * 4 + a;
    if (node < n) {
      float d = dis[node];
      __half2* dst = (__half2*)(y + (size_t)node * NCLS + tc * 4);
      dst[0] = __floats2half2_rn(d * acc[a][0], d * acc[a][1]);
      dst[1] = __floats2half2_rn(d * acc[a][2], d * acc[a][3]);
    }
  }
}

// one hop with RAW weights over fp16: acc = yin[c] + sum w_e * yin[row_e].
// FINAL=0: write fp16 dis^2 * acc.  FINAL=1: write f32 dis * acc + bias.
template <int FINAL>
__global__ void k_hop(const __half* __restrict__ yin, __half* __restrict__ youth,
                      float* __restrict__ youtf, const int* __restrict__ offx,
                      const int2* __restrict__ csc, const float* __restrict__ dis,
                      const float* __restrict__ bias, int n) {
  int node = (blockIdx.x * blockDim.x + threadIdx.x) >> 6;
  int lane = threadIdx.x & 63;
  if (node >= n) return;
  int beg = offx[node];
  int end = offx[node + 1];
  float acc = __half2float(yin[(size_t)node * NCLS + lane]);  // self loop, w=1

  for (int base = beg; base < end; base += 64) {
    int cnt = min(64, end - base);
    int2 m = make_int2(0, 0);
    if (lane < cnt) m = csc[base + lane];
    int e = 0;
    for (; e + 8 <= cnt; e += 8) {
      int r[8];
      float wv[8], v[8];
#pragma unroll
      for (int j = 0; j < 8; ++j) {
        r[j] = __builtin_amdgcn_readlane(m.x, e + j);
        wv[j] = __int_as_float(__builtin_amdgcn_readlane(m.y, e + j));
      }
#pragma unroll
      for (int j = 0; j < 8; ++j)
        v[j] = __half2float(yin[(size_t)r[j] * NCLS + lane]);
#pragma unroll
      for (int j = 0; j < 8; ++j) acc += wv[j] * v[j];
    }
    for (; e < cnt; ++e) {
      int r = __builtin_amdgcn_readlane(m.x, e);
      float wv = __int_as_float(__builtin_amdgcn_readlane(m.y, e));
      acc += wv * __half2float(yin[(size_t)r * NCLS + lane]);
    }
  }
  float d = dis[node];
  if (FINAL) {
    youtf[(size_t)node * NCLS + lane] = d * acc + bias[lane];
  } else {
    youth[(size_t)node * NCLS + lane] = __float2half(d * d * acc);
  }
}

// ---------------- launch ----------------

extern "C" void kernel_launch(void* const* d_in, const int* in_sizes, int n_in,
                              void* d_out, int out_size, void* d_ws, size_t ws_size,
                              hipStream_t stream) {
  (void)n_in; (void)out_size; (void)ws_size;
  const float* x  = (const float*)d_in[0];
  const void*  ei = d_in[1];
  const float* ew = (const float*)d_in[2];
  const float* lw = (const float*)d_in[3];
  const float* lb = (const float*)d_in[4];
  float* out = (float*)d_out;

  int n   = in_sizes[0] / NFEAT;
  int nnz = in_sizes[1] / 2;
  int nb  = (n + BCOLS - 1) >> BSH;       // buckets of 128 cols (<=1024)
  int eb  = (nnz + NBLK - 1) / NBLK;      // edges per block in A/B

  char* p = (char*)d_ws;
  auto carve = [&](size_t bytes) -> char* {
    char* r = p;
    p += (bytes + 255) & ~(size_t)255;
    return r;
  };
  int*    bcnt  = (int*)carve((size_t)NBLK * nb * 4);
  int*    tot   = (int*)carve((size_t)nb * 4);
  int*    offx  = (int*)carve((size_t)(n + 1) * 4);
  float*  dis   = (float*)carve((size_t)n * 4);
  int2*   csc   = (int2*)carve((size_t)nnz * 8);
  __half* y0    = (__half*)carve((size_t)n * NCLS * 2);
  __half* y1    = (__half*)carve((size_t)n * NCLS * 2);
  // ebuf (nnz * 8B = 12.8 MB) aliases d_out (25.6 MB); dead before the final
  // hop writes d_out.
  u64*    ebuf  = (u64*)d_out;

  int gw = (n + 3) / 4;               // hop: 4 node-waves per 256-thread block
  int gg = (n + TM - 1) / TM;         // gemm tiles

  k_bcount<<<NBLK, 256, nb * 4, stream>>>(ei, bcnt, nnz, nb, eb);
  k_colscan<<<nb, NBLK, 0, stream>>>(bcnt, tot, nb);
  k_bscatter<<<NBLK, 256, nb * 4, stream>>>(ei, ew, bcnt, tot, ebuf, nnz, nb, eb);
  k_bbuild<<<nb, 256, 0, stream>>>(ebuf, tot, offx, dis, csc, n, nb, nnz);
  k_gemm<<<gg, 256, 0, stream>>>(x, lw, dis, y0, n);
  k_hop<0><<<gw, 256, 0, stream>>>(y0, y1, nullptr, offx, csc, dis, nullptr, n);
  k_hop<1><<<gw, 256, 0, stream>>>(y1, nullptr, out, offx, csc, dis, lb, n);
}